// Round 14
// baseline (130.771 us; speedup 1.0000x reference)
//
#include <hip/hip_runtime.h>
#include <math.h>

#define IMG   256
#define NFULL 177
#define DETN  362
#define NACQ  45
#define PAD   1024

// ws layout (floats): [0,131072) sino ; [131072,262144) sf
#define SINO_OFF 0
#define SF_OFF   131072

// TTILE=64 x SEG=64 window: x/y spans both = 63(|c|+|s|)+5 <= 94 ->
// pitch <= 100, area <= 100*94 = 9400 floats. LDSF=9472 (37.9 KB) ->
// 4 blocks/CU x 8 waves = 32 waves/CU (100% cap).
#define LDSF  9472
#define TTILE 64
#define SEG   64
#define HALF_T 180.5f  // (DETN-1)/2

// ---------------------------------------------------------------------------
// Kernel A: radon staged directly from the original image (R12 staging form).
// Per-float4 clamp+mask staging (every cell of [0,4*w4)x[0,h) written each
// segment); 4-aligned origin => per-float4 validity is all-or-nothing.
// Block = (b,angle) x 64-T tile, 512 thr = 64 T x 8 S-phase.
// blockIdx.y remapped so long (central) T-tiles dispatch first.
__constant__ const int kByOrder[6] = {2, 3, 1, 4, 0, 5};

__global__ __launch_bounds__(512) void radon_kernel(
    const float* __restrict__ x,       // (2,1,256,256)
    const float* __restrict__ thetas,  // (177)
    float* __restrict__ sino)          // (2,177,362)
{
    const int blk = blockIdx.x;        // b*NFULL + a
    const int b = blk / NFULL;
    const int a = blk - b * NFULL;
    const int T0 = kByOrder[blockIdx.y] * TTILE;
    const int tid = threadIdx.x;
    const int ts = tid & 7;            // S phase
    const int tt = tid >> 3;           // T within tile (0..63)
    const int T = T0 + tt;

    __shared__ __align__(16) float tile[LDSF];
    __shared__ int sRange[2];

    const float th = thetas[a] * (float)(M_PI / 180.0);
    const float c = cosf(th);
    const float s = sinf(th);
    const float cx = (IMG - 1) * 0.5f;
    const float cy = (IMG - 1) * 0.5f;
    const float Tc = (float)T - HALF_T;
    const float xbase = Tc * c + cx;   // xs = xbase - sval*s
    const float ybase = Tc * s + cy;   // ys = ybase + sval*c

    // per-thread valid-S clipping (footprint can touch image) -> block union
    float lo = -1e30f, hi = 1e30f;
    bool empty = (T >= DETN);
    {   const float aa = -s;
        if (aa > 1e-5f)       { lo = fmaxf(lo, (-1.0f - xbase) / aa); hi = fminf(hi, (256.0f - xbase) / aa); }
        else if (aa < -1e-5f) { lo = fmaxf(lo, (256.0f - xbase) / aa); hi = fminf(hi, (-1.0f - xbase) / aa); }
        else if (xbase <= -1.0f || xbase >= 256.0f) empty = true;
    }
    {   const float aa = c;
        if (aa > 1e-5f)       { lo = fmaxf(lo, (-1.0f - ybase) / aa); hi = fminf(hi, (256.0f - ybase) / aa); }
        else if (aa < -1e-5f) { lo = fmaxf(lo, (256.0f - ybase) / aa); hi = fminf(hi, (-1.0f - ybase) / aa); }
        else if (ybase <= -1.0f || ybase >= 256.0f) empty = true;
    }
    lo = fmaxf(lo, -200.0f);
    hi = fminf(hi, 200.0f);
    int Slo = max(0, (int)floorf(lo + HALF_T) - 1);
    int Shi = min(DETN, (int)floorf(hi + HALF_T) + 2);
    if (empty || Shi < Slo) { Slo = 0; Shi = 0; }

    if (tid == 0) { sRange[0] = DETN; sRange[1] = 0; }
    __syncthreads();
    if (Shi > Slo) { atomicMin(&sRange[0], Slo); atomicMax(&sRange[1], Shi); }
    __syncthreads();
    const int SloB = sRange[0], ShiB = sRange[1];

    const float* __restrict__ img = x + b * IMG * IMG;

    // hoisted tile-corner terms (T extremes of this tile)
    const float TcA = (float)T0 - HALF_T;
    const float TcB = (float)(T0 + TTILE - 1) - HALF_T;
    const float xAB_mn = fminf(TcA * c + cx, TcB * c + cx);
    const float xAB_mx = fmaxf(TcA * c + cx, TcB * c + cx);
    const float yAB_mn = fminf(TcA * s + cy, TcB * s + cy);
    const float yAB_mx = fmaxf(TcA * s + cy, TcB * s + cy);

    float val = 0.0f;
    int Sseg = SloB;
    while (Sseg < ShiB) {
        const int Send = min(Sseg + SEG, ShiB);
        // AABB for the fixed 64-span (superset for tails)
        const float sv0 = (float)Sseg - HALF_T;
        const float sv1 = sv0 + (float)(SEG - 1);
        const float sx0 = sv0 * s, sx1 = sv1 * s;
        const float cy0 = sv0 * c, cy1 = sv1 * c;
        const float xmn = xAB_mn - fmaxf(sx0, sx1);
        const float xmx = xAB_mx - fminf(sx0, sx1);
        const float ymn = yAB_mn + fminf(cy0, cy1);
        const float ymx = yAB_mx + fmaxf(cy0, cy1);
        const int ix0 = (int)floorf(xmn) - 1;
        const int iy0 = (int)floorf(ymn) - 1;
        const int w = (int)floorf(xmx) + 3 - ix0;
        const int h = (int)floorf(ymx) + 3 - iy0;

        // 4-aligned window x-origin (image coords; & ~3 floors negatives too)
        const int ix0a = ix0 & ~3;
        const int wal  = (ix0 + w) - ix0a;     // <= 97
        const int w4   = (wal + 3) >> 2;       // <= 25
        int pitchd = w4 << 2;
        if ((pitchd & 31) == 0) pitchd += 4;   // dodge bank-periodic rows
        const int total4 = w4 * h;             // <= 2350
        const unsigned magic = (1u << 22) / (unsigned)w4 + 1;  // exact: d<=25 here

        // stage: clamped float4 loads + validity mask -> every cell written
        for (int f = tid; f < total4; f += 512) {
            const int r  = (int)(((unsigned)f * magic) >> 22);
            const int c4 = f - r * w4;
            const int gy = iy0 + r;
            const int gx = ix0a + (c4 << 2);           // 4-aligned: all-or-nothing
            const int cyc = min(max(gy, 0), IMG - 1);
            const int cxc = min(max(gx, 0), IMG - 4);
            float4 v = *(const float4*)(img + cyc * IMG + cxc);
            const bool ok = ((unsigned)gy < (unsigned)IMG) &
                            ((unsigned)gx <= (unsigned)(IMG - 4));
            if (!ok) v = make_float4(0.f, 0.f, 0.f, 0.f);
            *(float4*)(tile + r * pitchd + (c4 << 2)) = v;
        }
        __syncthreads();

        const float xoff = xbase - (float)ix0a;
        const float yoff = ybase - (float)iy0;
        if (Send - Sseg == SEG) {
            const float s0 = (float)(Sseg + ts) - HALF_T;
            #pragma unroll 4
            for (int u = 0; u < 8; ++u) {
                const float sval = s0 + (float)(8 * u);
                const float xs = fmaf(-sval, s, xoff);
                const float ys = fmaf(sval, c, yoff);
                const float x0f = floorf(xs);
                const float y0f = floorf(ys);
                const float wx = xs - x0f;
                const float wy = ys - y0f;
                const int base = (int)y0f * pitchd + (int)x0f;
                const float v00 = tile[base];
                const float v01 = tile[base + 1];
                const float v10 = tile[base + pitchd];
                const float v11 = tile[base + pitchd + 1];
                const float h0 = fmaf(wx, v01 - v00, v00);
                const float h1 = fmaf(wx, v11 - v10, v10);
                val += fmaf(wy, h1 - h0, h0);
            }
        } else {
            for (int S = Sseg + ts; S < Send; S += 8) {
                const float sval = (float)S - HALF_T;
                const float xs = fmaf(-sval, s, xoff);
                const float ys = fmaf(sval, c, yoff);
                const float x0f = floorf(xs);
                const float y0f = floorf(ys);
                const float wx = xs - x0f;
                const float wy = ys - y0f;
                const int base = (int)y0f * pitchd + (int)x0f;
                const float v00 = tile[base];
                const float v01 = tile[base + 1];
                const float v10 = tile[base + pitchd];
                const float v11 = tile[base + pitchd + 1];
                const float h0 = fmaf(wx, v01 - v00, v00);
                const float h1 = fmaf(wx, v11 - v10, v10);
                val += fmaf(wy, h1 - h0, h0);
            }
        }
        __syncthreads();
        Sseg += SEG;
    }

    val += __shfl_xor(val, 1, 8);
    val += __shfl_xor(val, 2, 8);
    val += __shfl_xor(val, 4, 8);
    if (ts == 0 && T < DETN) {
        sino[(b * NFULL + a) * DETN + T] = val;
    }
}

// ---------------------------------------------------------------------------
// Kernel B: data-consistency + ramp filter (scale folded in; odd taps only).
__global__ __launch_bounds__(192) void dc_filter_kernel(
    const float* __restrict__ sino,
    const float* __restrict__ st,
    const int*   __restrict__ acq,
    float* __restrict__ sf)
{
    const int blk = blockIdx.x;
    const int b = blk / NFULL;
    const int a = blk - b * NFULL;
    const int tid = threadIdx.x;

    __shared__ float col[DETN];
    __shared__ float gf[PAD];

    const float SC = (float)(M_PI / (2.0 * NFULL));
    const float c0 = 0.5f * SC;
    for (int n = tid; n < PAD; n += 192) {
        float v = 0.0f;
        if (n & 1) {
            const int d = (n < PAD - n) ? n : (PAD - n);
            const float pd = (float)M_PI * (float)d;
            v = -2.0f / (pd * pd) * SC;
        }
        gf[n] = v;
    }

    int inv = -1;
    for (int i = 0; i < NACQ; ++i) {
        if (acq[i] == a) inv = i;
    }

    for (int m = tid; m < DETN; m += 192) {
        float val = sino[(b * NFULL + a) * DETN + m];
        if (inv >= 0) {
            val = st[(b * DETN + m) * NACQ + inv] - val;
        }
        col[m] = val;
    }
    __syncthreads();

    const int T = blockIdx.y * 181 + tid;     // halves: [0,181) and [181,362)
    if (tid < 181) {
        const int m0 = (T + 1) & 1;           // opposite parity -> odd (T-m)
        float acc = c0 * col[T];
        #pragma unroll 4
        for (int k = 0; k < 181; ++k) {
            const int m = m0 + 2 * k;
            acc += col[m] * gf[(T - m) & (PAD - 1)];
        }
        sf[(b * NFULL + a) * DETN + T] = acc;
    }
}

// ---------------------------------------------------------------------------
// Kernel C: backprojection. Block = 64 pixels (same row) x 4 angle-phases.
// t0 in [0,360] always; {cos, sn*gy+H} packed pairs in LDS.
__global__ __launch_bounds__(256) void backproject_kernel(
    const float* __restrict__ sf,
    const float* __restrict__ thetas,
    float* __restrict__ out)
{
    __shared__ float cb[2 * NFULL];
    __shared__ float red[256];
    const int tid = threadIdx.x;
    const int lane  = tid & 63;
    const int phase = tid >> 6;
    const int pix = blockIdx.x * 64 + lane;          // b*65536 + y*256 + x
    const int b = pix >> 16;
    const int y = (pix >> 8) & 255;
    const int xq = pix & 255;
    const float gx = (float)xq - (IMG - 1) * 0.5f;
    const float gy = (float)y  - (IMG - 1) * 0.5f;   // uniform across block

    for (int a = tid; a < NFULL; a += 256) {
        float th = thetas[a] * (float)(M_PI / 180.0);
        cb[2 * a]     = cosf(th);
        cb[2 * a + 1] = fmaf(sinf(th), gy, HALF_T);
    }
    __syncthreads();

    const float* __restrict__ sfb = sf + b * NFULL * DETN;

    float acc = 0.0f;
    #pragma unroll 4
    for (int a = phase; a < NFULL; a += 4) {
        const float cs = cb[2 * a];
        const float bs = cb[2 * a + 1];
        const float t = fmaf(cs, gx, bs);
        const float t0f = floorf(t);
        const float w = t - t0f;
        const float* row = sfb + a * DETN + (int)t0f;
        const float v0 = row[0];
        const float v1 = row[1];
        acc += v0 + w * (v1 - v0);
    }
    red[tid] = acc;
    __syncthreads();
    if (tid < 64) {
        out[blockIdx.x * 64 + tid] =
            red[tid] + red[tid + 64] + red[tid + 128] + red[tid + 192];
    }
}

extern "C" void kernel_launch(void* const* d_in, const int* in_sizes, int n_in,
                              void* d_out, int out_size, void* d_ws, size_t ws_size,
                              hipStream_t stream) {
    const float* x      = (const float*)d_in[0];
    const float* st     = (const float*)d_in[1];
    const float* thetas = (const float*)d_in[2];
    const int*   acq    = (const int*)d_in[3];
    float* out  = (float*)d_out;
    float* wsf  = (float*)d_ws;
    float* sino = wsf + SINO_OFF;
    float* sf   = wsf + SF_OFF;

    dim3 gA(2 * NFULL, (DETN + TTILE - 1) / TTILE);   // 354 x 6
    radon_kernel<<<gA, 512, 0, stream>>>(x, thetas, sino);
    dim3 gB(2 * NFULL, 2);                            // 708 blocks
    dc_filter_kernel<<<gB, 192, 0, stream>>>(sino, st, acq, sf);
    backproject_kernel<<<(2 * IMG * IMG) / 64, 256, 0, stream>>>(sf, thetas, out);
}

// Round 15
// 126.832 us; speedup vs baseline: 1.0311x; 1.0311x over previous
//
#include <hip/hip_runtime.h>
#include <math.h>

#define IMG   256
#define NFULL 177
#define DETN  362
#define NACQ  45
#define PAD   1024

// ws layout (floats): [0,131072) sino ; [131072,262144) sf
#define SINO_OFF 0
#define SF_OFF   131072

// Tile capped at 5088 floats (20360 B -> 20480 B LDS block) -> 8 blocks/CU
// x 4 waves = 32 waves/CU (100% cap). SEG=64 used when its window fits
// (pitchd*h <= 5088, ~85% of angles); else SEG=48, which ALWAYS fits:
// span <= sqrt(31^2+47^2)+4 = 60.3 -> wal<=63, pitchd<=68, h<=61 -> 4148.
#define LDSF  5088
#define TTILE 32
#define SEG   64
#define SEGF  48
#define HALF_T 180.5f  // (DETN-1)/2

// ---------------------------------------------------------------------------
// Kernel A: radon staged directly from the original image (R12 form).
// Per-float4 clamp+mask staging (every cell of [0,4*w4)x[0,h) written each
// segment); 4-aligned origin => per-float4 validity is all-or-nothing.
// Block = (b,angle) x 32-T tile, 256 thr = 32 T x 8 S-phase.
// blockIdx.y remapped so long (central) T-tiles dispatch first.
__constant__ const int kByOrder[12] = {5, 6, 4, 7, 3, 8, 2, 9, 1, 10, 0, 11};

__global__ __launch_bounds__(256) void radon_kernel(
    const float* __restrict__ x,       // (2,1,256,256)
    const float* __restrict__ thetas,  // (177)
    float* __restrict__ sino)          // (2,177,362)
{
    const int blk = blockIdx.x;        // b*NFULL + a
    const int b = blk / NFULL;
    const int a = blk - b * NFULL;
    const int T0 = kByOrder[blockIdx.y] * TTILE;
    const int tid = threadIdx.x;
    const int ts = tid & 7;            // S phase
    const int tt = tid >> 3;           // T within tile (0..31)
    const int T = T0 + tt;

    __shared__ __align__(16) float tile[LDSF];
    __shared__ int sRange[2];

    const float th = thetas[a] * (float)(M_PI / 180.0);
    const float c = cosf(th);
    const float s = sinf(th);
    const float cx = (IMG - 1) * 0.5f;
    const float cy = (IMG - 1) * 0.5f;
    const float Tc = (float)T - HALF_T;
    const float xbase = Tc * c + cx;   // xs = xbase - sval*s
    const float ybase = Tc * s + cy;   // ys = ybase + sval*c

    // per-thread valid-S clipping (footprint can touch image) -> block union
    float lo = -1e30f, hi = 1e30f;
    bool empty = (T >= DETN);
    {   const float aa = -s;
        if (aa > 1e-5f)       { lo = fmaxf(lo, (-1.0f - xbase) / aa); hi = fminf(hi, (256.0f - xbase) / aa); }
        else if (aa < -1e-5f) { lo = fmaxf(lo, (256.0f - xbase) / aa); hi = fminf(hi, (-1.0f - xbase) / aa); }
        else if (xbase <= -1.0f || xbase >= 256.0f) empty = true;
    }
    {   const float aa = c;
        if (aa > 1e-5f)       { lo = fmaxf(lo, (-1.0f - ybase) / aa); hi = fminf(hi, (256.0f - ybase) / aa); }
        else if (aa < -1e-5f) { lo = fmaxf(lo, (256.0f - ybase) / aa); hi = fminf(hi, (-1.0f - ybase) / aa); }
        else if (ybase <= -1.0f || ybase >= 256.0f) empty = true;
    }
    lo = fmaxf(lo, -200.0f);
    hi = fminf(hi, 200.0f);
    int Slo = max(0, (int)floorf(lo + HALF_T) - 1);
    int Shi = min(DETN, (int)floorf(hi + HALF_T) + 2);
    if (empty || Shi < Slo) { Slo = 0; Shi = 0; }

    if (tid == 0) { sRange[0] = DETN; sRange[1] = 0; }
    __syncthreads();
    if (Shi > Slo) { atomicMin(&sRange[0], Slo); atomicMax(&sRange[1], Shi); }
    __syncthreads();
    const int SloB = sRange[0], ShiB = sRange[1];

    const float* __restrict__ img = x + b * IMG * IMG;

    // hoisted tile-corner terms (T extremes of this tile)
    const float TcA = (float)T0 - HALF_T;
    const float TcB = (float)(T0 + TTILE - 1) - HALF_T;
    const float xAB_mn = fminf(TcA * c + cx, TcB * c + cx);
    const float xAB_mx = fmaxf(TcA * c + cx, TcB * c + cx);
    const float yAB_mn = fminf(TcA * s + cy, TcB * s + cy);
    const float yAB_mx = fmaxf(TcA * s + cy, TcB * s + cy);

    float val = 0.0f;
    int Sseg = SloB;
    while (Sseg < ShiB) {
        // choose segment length: 64 if its window fits, else 48 (always fits)
        int segLen = SEG;
        int Send, ix0, iy0, w4, h, pitchd;
        for (int attempt = 0; attempt < 2; ++attempt) {
            Send = min(Sseg + segLen, ShiB);
            const float sv0 = (float)Sseg - HALF_T;
            const float sv1 = sv0 + (float)(segLen - 1);
            const float sx0 = sv0 * s, sx1 = sv1 * s;
            const float cy0 = sv0 * c, cy1 = sv1 * c;
            const float xmn = xAB_mn - fmaxf(sx0, sx1);
            const float xmx = xAB_mx - fminf(sx0, sx1);
            const float ymn = yAB_mn + fminf(cy0, cy1);
            const float ymx = yAB_mx + fmaxf(cy0, cy1);
            ix0 = (int)floorf(xmn) - 1;
            iy0 = (int)floorf(ymn) - 1;
            const int w = (int)floorf(xmx) + 3 - ix0;
            h = (int)floorf(ymx) + 3 - iy0;
            const int ix0a = ix0 & ~3;
            const int wal  = (ix0 + w) - ix0a;
            w4 = (wal + 3) >> 2;
            pitchd = w4 << 2;
            if ((pitchd & 31) == 0) pitchd += 4;   // dodge bank-periodic rows
            if (pitchd * h <= LDSF) break;
            segLen = SEGF;
        }
        const int ix0a = ix0 & ~3;
        const int total4 = w4 * h;
        const unsigned magic = (1u << 22) / (unsigned)w4 + 1;  // exact: d<=19

        // stage: clamped float4 loads + validity mask -> every cell written
        for (int f = tid; f < total4; f += 256) {
            const int r  = (int)(((unsigned)f * magic) >> 22);
            const int c4 = f - r * w4;
            const int gy = iy0 + r;
            const int gx = ix0a + (c4 << 2);           // 4-aligned: all-or-nothing
            const int cyc = min(max(gy, 0), IMG - 1);
            const int cxc = min(max(gx, 0), IMG - 4);
            float4 v = *(const float4*)(img + cyc * IMG + cxc);
            const bool ok = ((unsigned)gy < (unsigned)IMG) &
                            ((unsigned)gx <= (unsigned)(IMG - 4));
            if (!ok) v = make_float4(0.f, 0.f, 0.f, 0.f);
            *(float4*)(tile + r * pitchd + (c4 << 2)) = v;
        }
        __syncthreads();

        const float xoff = xbase - (float)ix0a;
        const float yoff = ybase - (float)iy0;
        if (Send - Sseg == SEG) {
            const float s0 = (float)(Sseg + ts) - HALF_T;
            #pragma unroll 4
            for (int u = 0; u < 8; ++u) {
                const float sval = s0 + (float)(8 * u);
                const float xs = fmaf(-sval, s, xoff);
                const float ys = fmaf(sval, c, yoff);
                const float x0f = floorf(xs);
                const float y0f = floorf(ys);
                const float wx = xs - x0f;
                const float wy = ys - y0f;
                const int base = (int)y0f * pitchd + (int)x0f;
                const float v00 = tile[base];
                const float v01 = tile[base + 1];
                const float v10 = tile[base + pitchd];
                const float v11 = tile[base + pitchd + 1];
                const float h0 = fmaf(wx, v01 - v00, v00);
                const float h1 = fmaf(wx, v11 - v10, v10);
                val += fmaf(wy, h1 - h0, h0);
            }
        } else {
            for (int S = Sseg + ts; S < Send; S += 8) {
                const float sval = (float)S - HALF_T;
                const float xs = fmaf(-sval, s, xoff);
                const float ys = fmaf(sval, c, yoff);
                const float x0f = floorf(xs);
                const float y0f = floorf(ys);
                const float wx = xs - x0f;
                const float wy = ys - y0f;
                const int base = (int)y0f * pitchd + (int)x0f;
                const float v00 = tile[base];
                const float v01 = tile[base + 1];
                const float v10 = tile[base + pitchd];
                const float v11 = tile[base + pitchd + 1];
                const float h0 = fmaf(wx, v01 - v00, v00);
                const float h1 = fmaf(wx, v11 - v10, v10);
                val += fmaf(wy, h1 - h0, h0);
            }
        }
        __syncthreads();
        Sseg = Send;
    }

    val += __shfl_xor(val, 1, 8);
    val += __shfl_xor(val, 2, 8);
    val += __shfl_xor(val, 4, 8);
    if (ts == 0 && T < DETN) {
        sino[(b * NFULL + a) * DETN + T] = val;
    }
}

// ---------------------------------------------------------------------------
// Kernel B: data-consistency + ramp filter (scale folded in; odd taps only).
__global__ __launch_bounds__(192) void dc_filter_kernel(
    const float* __restrict__ sino,
    const float* __restrict__ st,
    const int*   __restrict__ acq,
    float* __restrict__ sf)
{
    const int blk = blockIdx.x;
    const int b = blk / NFULL;
    const int a = blk - b * NFULL;
    const int tid = threadIdx.x;

    __shared__ float col[DETN];
    __shared__ float gf[PAD];

    const float SC = (float)(M_PI / (2.0 * NFULL));
    const float c0 = 0.5f * SC;
    for (int n = tid; n < PAD; n += 192) {
        float v = 0.0f;
        if (n & 1) {
            const int d = (n < PAD - n) ? n : (PAD - n);
            const float pd = (float)M_PI * (float)d;
            v = -2.0f / (pd * pd) * SC;
        }
        gf[n] = v;
    }

    int inv = -1;
    for (int i = 0; i < NACQ; ++i) {
        if (acq[i] == a) inv = i;
    }

    for (int m = tid; m < DETN; m += 192) {
        float val = sino[(b * NFULL + a) * DETN + m];
        if (inv >= 0) {
            val = st[(b * DETN + m) * NACQ + inv] - val;
        }
        col[m] = val;
    }
    __syncthreads();

    const int T = blockIdx.y * 181 + tid;     // halves: [0,181) and [181,362)
    if (tid < 181) {
        const int m0 = (T + 1) & 1;           // opposite parity -> odd (T-m)
        float acc = c0 * col[T];
        #pragma unroll 4
        for (int k = 0; k < 181; ++k) {
            const int m = m0 + 2 * k;
            acc += col[m] * gf[(T - m) & (PAD - 1)];
        }
        sf[(b * NFULL + a) * DETN + T] = acc;
    }
}

// ---------------------------------------------------------------------------
// Kernel C: backprojection. Block = 64 pixels (same row) x 4 angle-phases.
// t0 in [0,360] always; {cos, sn*gy+H} packed pairs in LDS.
__global__ __launch_bounds__(256) void backproject_kernel(
    const float* __restrict__ sf,
    const float* __restrict__ thetas,
    float* __restrict__ out)
{
    __shared__ float cb[2 * NFULL];
    __shared__ float red[256];
    const int tid = threadIdx.x;
    const int lane  = tid & 63;
    const int phase = tid >> 6;
    const int pix = blockIdx.x * 64 + lane;          // b*65536 + y*256 + x
    const int b = pix >> 16;
    const int y = (pix >> 8) & 255;
    const int xq = pix & 255;
    const float gx = (float)xq - (IMG - 1) * 0.5f;
    const float gy = (float)y  - (IMG - 1) * 0.5f;   // uniform across block

    for (int a = tid; a < NFULL; a += 256) {
        float th = thetas[a] * (float)(M_PI / 180.0);
        cb[2 * a]     = cosf(th);
        cb[2 * a + 1] = fmaf(sinf(th), gy, HALF_T);
    }
    __syncthreads();

    const float* __restrict__ sfb = sf + b * NFULL * DETN;

    float acc = 0.0f;
    #pragma unroll 4
    for (int a = phase; a < NFULL; a += 4) {
        const float cs = cb[2 * a];
        const float bs = cb[2 * a + 1];
        const float t = fmaf(cs, gx, bs);
        const float t0f = floorf(t);
        const float w = t - t0f;
        const float* row = sfb + a * DETN + (int)t0f;
        const float v0 = row[0];
        const float v1 = row[1];
        acc += v0 + w * (v1 - v0);
    }
    red[tid] = acc;
    __syncthreads();
    if (tid < 64) {
        out[blockIdx.x * 64 + tid] =
            red[tid] + red[tid + 64] + red[tid + 128] + red[tid + 192];
    }
}

extern "C" void kernel_launch(void* const* d_in, const int* in_sizes, int n_in,
                              void* d_out, int out_size, void* d_ws, size_t ws_size,
                              hipStream_t stream) {
    const float* x      = (const float*)d_in[0];
    const float* st     = (const float*)d_in[1];
    const float* thetas = (const float*)d_in[2];
    const int*   acq    = (const int*)d_in[3];
    float* out  = (float*)d_out;
    float* wsf  = (float*)d_ws;
    float* sino = wsf + SINO_OFF;
    float* sf   = wsf + SF_OFF;

    dim3 gA(2 * NFULL, (DETN + TTILE - 1) / TTILE);   // 354 x 12
    radon_kernel<<<gA, 256, 0, stream>>>(x, thetas, sino);
    dim3 gB(2 * NFULL, 2);                            // 708 blocks
    dc_filter_kernel<<<gB, 192, 0, stream>>>(sino, st, acq, sf);
    backproject_kernel<<<(2 * IMG * IMG) / 64, 256, 0, stream>>>(sf, thetas, out);
}

// Round 16
// 126.756 us; speedup vs baseline: 1.0317x; 1.0006x over previous
//
#include <hip/hip_runtime.h>
#include <math.h>

#define IMG   256
#define NFULL 177
#define DETN  362
#define NACQ  45
#define PAD   1024

// ws layout (floats): [0,131072) sino ; [131072,262144) sf
#define SINO_OFF 0
#define SF_OFF   131072

// Tile capped at 5088 floats (20480 B LDS block) -> 8 blocks/CU x 4 waves
// = 32 waves/CU. SEG=64 when its window fits; else SEG=48 which ALWAYS fits
// even with the odd-pitch bump: w4<=16 -> pitchd<=68, h<=61 -> 4148 <= 5088.
// Pitch rule: pitchd/4 forced ODD -> row stride 4*odd, tap-pair banks never
// collide and the (tt,ts) lane-delta lattice loses mod-8 degeneracy.
#define LDSF  5088
#define TTILE 32
#define SEG   64
#define SEGF  48
#define HALF_T 180.5f  // (DETN-1)/2

// ---------------------------------------------------------------------------
// Kernel A: radon staged directly from the original image (R12 form).
// Per-float4 clamp+mask staging (every cell of [0,4*w4)x[0,h) written each
// segment); 4-aligned origin => per-float4 validity is all-or-nothing.
// Block = (b,angle) x 32-T tile, 256 thr = 32 T x 8 S-phase.
// blockIdx.y remapped so long (central) T-tiles dispatch first.
__constant__ const int kByOrder[12] = {5, 6, 4, 7, 3, 8, 2, 9, 1, 10, 0, 11};

__global__ __launch_bounds__(256) void radon_kernel(
    const float* __restrict__ x,       // (2,1,256,256)
    const float* __restrict__ thetas,  // (177)
    float* __restrict__ sino)          // (2,177,362)
{
    const int blk = blockIdx.x;        // b*NFULL + a
    const int b = blk / NFULL;
    const int a = blk - b * NFULL;
    const int T0 = kByOrder[blockIdx.y] * TTILE;
    const int tid = threadIdx.x;
    const int ts = tid & 7;            // S phase
    const int tt = tid >> 3;           // T within tile (0..31)
    const int T = T0 + tt;

    __shared__ __align__(16) float tile[LDSF];
    __shared__ int sRange[2];

    const float th = thetas[a] * (float)(M_PI / 180.0);
    const float c = cosf(th);
    const float s = sinf(th);
    const float cx = (IMG - 1) * 0.5f;
    const float cy = (IMG - 1) * 0.5f;
    const float Tc = (float)T - HALF_T;
    const float xbase = Tc * c + cx;   // xs = xbase - sval*s
    const float ybase = Tc * s + cy;   // ys = ybase + sval*c

    // per-thread valid-S clipping (footprint can touch image) -> block union
    float lo = -1e30f, hi = 1e30f;
    bool empty = (T >= DETN);
    {   const float aa = -s;
        if (aa > 1e-5f)       { lo = fmaxf(lo, (-1.0f - xbase) / aa); hi = fminf(hi, (256.0f - xbase) / aa); }
        else if (aa < -1e-5f) { lo = fmaxf(lo, (256.0f - xbase) / aa); hi = fminf(hi, (-1.0f - xbase) / aa); }
        else if (xbase <= -1.0f || xbase >= 256.0f) empty = true;
    }
    {   const float aa = c;
        if (aa > 1e-5f)       { lo = fmaxf(lo, (-1.0f - ybase) / aa); hi = fminf(hi, (256.0f - ybase) / aa); }
        else if (aa < -1e-5f) { lo = fmaxf(lo, (256.0f - ybase) / aa); hi = fminf(hi, (-1.0f - ybase) / aa); }
        else if (ybase <= -1.0f || ybase >= 256.0f) empty = true;
    }
    lo = fmaxf(lo, -200.0f);
    hi = fminf(hi, 200.0f);
    int Slo = max(0, (int)floorf(lo + HALF_T) - 1);
    int Shi = min(DETN, (int)floorf(hi + HALF_T) + 2);
    if (empty || Shi < Slo) { Slo = 0; Shi = 0; }

    if (tid == 0) { sRange[0] = DETN; sRange[1] = 0; }
    __syncthreads();
    if (Shi > Slo) { atomicMin(&sRange[0], Slo); atomicMax(&sRange[1], Shi); }
    __syncthreads();
    const int SloB = sRange[0], ShiB = sRange[1];

    const float* __restrict__ img = x + b * IMG * IMG;

    // hoisted tile-corner terms (T extremes of this tile)
    const float TcA = (float)T0 - HALF_T;
    const float TcB = (float)(T0 + TTILE - 1) - HALF_T;
    const float xAB_mn = fminf(TcA * c + cx, TcB * c + cx);
    const float xAB_mx = fmaxf(TcA * c + cx, TcB * c + cx);
    const float yAB_mn = fminf(TcA * s + cy, TcB * s + cy);
    const float yAB_mx = fmaxf(TcA * s + cy, TcB * s + cy);

    float val = 0.0f;
    int Sseg = SloB;
    while (Sseg < ShiB) {
        // choose segment length: 64 if its window fits, else 48 (always fits)
        int segLen = SEG;
        int Send, ix0, iy0, w4, h, pitchd;
        for (int attempt = 0; attempt < 2; ++attempt) {
            Send = min(Sseg + segLen, ShiB);
            const float sv0 = (float)Sseg - HALF_T;
            const float sv1 = sv0 + (float)(segLen - 1);
            const float sx0 = sv0 * s, sx1 = sv1 * s;
            const float cy0 = sv0 * c, cy1 = sv1 * c;
            const float xmn = xAB_mn - fmaxf(sx0, sx1);
            const float xmx = xAB_mx - fminf(sx0, sx1);
            const float ymn = yAB_mn + fminf(cy0, cy1);
            const float ymx = yAB_mx + fmaxf(cy0, cy1);
            ix0 = (int)floorf(xmn) - 1;
            iy0 = (int)floorf(ymn) - 1;
            const int w = (int)floorf(xmx) + 3 - ix0;
            h = (int)floorf(ymx) + 3 - iy0;
            const int ix0a = ix0 & ~3;
            const int wal  = (ix0 + w) - ix0a;
            w4 = (wal + 3) >> 2;
            pitchd = w4 << 2;
            if ((pitchd & 7) == 0) pitchd += 4;  // force pitchd/4 odd
            if (pitchd * h <= LDSF) break;
            segLen = SEGF;
        }
        const int ix0a = ix0 & ~3;
        const int total4 = w4 * h;
        const unsigned magic = (1u << 22) / (unsigned)w4 + 1;  // exact: d<=19

        // stage: clamped float4 loads + validity mask -> every cell written
        for (int f = tid; f < total4; f += 256) {
            const int r  = (int)(((unsigned)f * magic) >> 22);
            const int c4 = f - r * w4;
            const int gy = iy0 + r;
            const int gx = ix0a + (c4 << 2);           // 4-aligned: all-or-nothing
            const int cyc = min(max(gy, 0), IMG - 1);
            const int cxc = min(max(gx, 0), IMG - 4);
            float4 v = *(const float4*)(img + cyc * IMG + cxc);
            const bool ok = ((unsigned)gy < (unsigned)IMG) &
                            ((unsigned)gx <= (unsigned)(IMG - 4));
            if (!ok) v = make_float4(0.f, 0.f, 0.f, 0.f);
            *(float4*)(tile + r * pitchd + (c4 << 2)) = v;
        }
        __syncthreads();

        const float xoff = xbase - (float)ix0a;
        const float yoff = ybase - (float)iy0;
        if (Send - Sseg == SEG) {
            const float s0 = (float)(Sseg + ts) - HALF_T;
            #pragma unroll 4
            for (int u = 0; u < 8; ++u) {
                const float sval = s0 + (float)(8 * u);
                const float xs = fmaf(-sval, s, xoff);
                const float ys = fmaf(sval, c, yoff);
                const float x0f = floorf(xs);
                const float y0f = floorf(ys);
                const float wx = xs - x0f;
                const float wy = ys - y0f;
                const int base = (int)y0f * pitchd + (int)x0f;
                const float v00 = tile[base];
                const float v01 = tile[base + 1];
                const float v10 = tile[base + pitchd];
                const float v11 = tile[base + pitchd + 1];
                const float h0 = fmaf(wx, v01 - v00, v00);
                const float h1 = fmaf(wx, v11 - v10, v10);
                val += fmaf(wy, h1 - h0, h0);
            }
        } else {
            for (int S = Sseg + ts; S < Send; S += 8) {
                const float sval = (float)S - HALF_T;
                const float xs = fmaf(-sval, s, xoff);
                const float ys = fmaf(sval, c, yoff);
                const float x0f = floorf(xs);
                const float y0f = floorf(ys);
                const float wx = xs - x0f;
                const float wy = ys - y0f;
                const int base = (int)y0f * pitchd + (int)x0f;
                const float v00 = tile[base];
                const float v01 = tile[base + 1];
                const float v10 = tile[base + pitchd];
                const float v11 = tile[base + pitchd + 1];
                const float h0 = fmaf(wx, v01 - v00, v00);
                const float h1 = fmaf(wx, v11 - v10, v10);
                val += fmaf(wy, h1 - h0, h0);
            }
        }
        __syncthreads();
        Sseg = Send;
    }

    val += __shfl_xor(val, 1, 8);
    val += __shfl_xor(val, 2, 8);
    val += __shfl_xor(val, 4, 8);
    if (ts == 0 && T < DETN) {
        sino[(b * NFULL + a) * DETN + T] = val;
    }
}

// ---------------------------------------------------------------------------
// Kernel B: data-consistency + ramp filter (scale folded in; odd taps only).
__global__ __launch_bounds__(192) void dc_filter_kernel(
    const float* __restrict__ sino,
    const float* __restrict__ st,
    const int*   __restrict__ acq,
    float* __restrict__ sf)
{
    const int blk = blockIdx.x;
    const int b = blk / NFULL;
    const int a = blk - b * NFULL;
    const int tid = threadIdx.x;

    __shared__ float col[DETN];
    __shared__ float gf[PAD];

    const float SC = (float)(M_PI / (2.0 * NFULL));
    const float c0 = 0.5f * SC;
    for (int n = tid; n < PAD; n += 192) {
        float v = 0.0f;
        if (n & 1) {
            const int d = (n < PAD - n) ? n : (PAD - n);
            const float pd = (float)M_PI * (float)d;
            v = -2.0f / (pd * pd) * SC;
        }
        gf[n] = v;
    }

    int inv = -1;
    for (int i = 0; i < NACQ; ++i) {
        if (acq[i] == a) inv = i;
    }

    for (int m = tid; m < DETN; m += 192) {
        float val = sino[(b * NFULL + a) * DETN + m];
        if (inv >= 0) {
            val = st[(b * DETN + m) * NACQ + inv] - val;
        }
        col[m] = val;
    }
    __syncthreads();

    const int T = blockIdx.y * 181 + tid;     // halves: [0,181) and [181,362)
    if (tid < 181) {
        const int m0 = (T + 1) & 1;           // opposite parity -> odd (T-m)
        float acc = c0 * col[T];
        #pragma unroll 4
        for (int k = 0; k < 181; ++k) {
            const int m = m0 + 2 * k;
            acc += col[m] * gf[(T - m) & (PAD - 1)];
        }
        sf[(b * NFULL + a) * DETN + T] = acc;
    }
}

// ---------------------------------------------------------------------------
// Kernel C: backprojection. Block = 64 pixels (same row) x 4 angle-phases.
// t0 in [0,360] always; {cos, sn*gy+H} packed pairs in LDS.
__global__ __launch_bounds__(256) void backproject_kernel(
    const float* __restrict__ sf,
    const float* __restrict__ thetas,
    float* __restrict__ out)
{
    __shared__ float cb[2 * NFULL];
    __shared__ float red[256];
    const int tid = threadIdx.x;
    const int lane  = tid & 63;
    const int phase = tid >> 6;
    const int pix = blockIdx.x * 64 + lane;          // b*65536 + y*256 + x
    const int b = pix >> 16;
    const int y = (pix >> 8) & 255;
    const int xq = pix & 255;
    const float gx = (float)xq - (IMG - 1) * 0.5f;
    const float gy = (float)y  - (IMG - 1) * 0.5f;   // uniform across block

    for (int a = tid; a < NFULL; a += 256) {
        float th = thetas[a] * (float)(M_PI / 180.0);
        cb[2 * a]     = cosf(th);
        cb[2 * a + 1] = fmaf(sinf(th), gy, HALF_T);
    }
    __syncthreads();

    const float* __restrict__ sfb = sf + b * NFULL * DETN;

    float acc = 0.0f;
    #pragma unroll 4
    for (int a = phase; a < NFULL; a += 4) {
        const float cs = cb[2 * a];
        const float bs = cb[2 * a + 1];
        const float t = fmaf(cs, gx, bs);
        const float t0f = floorf(t);
        const float w = t - t0f;
        const float* row = sfb + a * DETN + (int)t0f;
        const float v0 = row[0];
        const float v1 = row[1];
        acc += v0 + w * (v1 - v0);
    }
    red[tid] = acc;
    __syncthreads();
    if (tid < 64) {
        out[blockIdx.x * 64 + tid] =
            red[tid] + red[tid + 64] + red[tid + 128] + red[tid + 192];
    }
}

extern "C" void kernel_launch(void* const* d_in, const int* in_sizes, int n_in,
                              void* d_out, int out_size, void* d_ws, size_t ws_size,
                              hipStream_t stream) {
    const float* x      = (const float*)d_in[0];
    const float* st     = (const float*)d_in[1];
    const float* thetas = (const float*)d_in[2];
    const int*   acq    = (const int*)d_in[3];
    float* out  = (float*)d_out;
    float* wsf  = (float*)d_ws;
    float* sino = wsf + SINO_OFF;
    float* sf   = wsf + SF_OFF;

    dim3 gA(2 * NFULL, (DETN + TTILE - 1) / TTILE);   // 354 x 12
    radon_kernel<<<gA, 256, 0, stream>>>(x, thetas, sino);
    dim3 gB(2 * NFULL, 2);                            // 708 blocks
    dc_filter_kernel<<<gB, 192, 0, stream>>>(sino, st, acq, sf);
    backproject_kernel<<<(2 * IMG * IMG) / 64, 256, 0, stream>>>(sf, thetas, out);
}